// Round 17
// baseline (1001.339 us; speedup 1.0000x reference)
//
#include <hip/hip_runtime.h>

#define T_STEPS 250
#define BATCH   256
#define IN_DIM  700
#define HID     1024
#define W_LD    1724   // = IN_DIM + HID
#define OUT_DIM 20
#define KP      704    // K padded to 22*32
#define NKT     (KP / 32)
#define MAXCT   55     // largest chunk

typedef __attribute__((ext_vector_type(8))) short     bf16x8;
typedef __attribute__((ext_vector_type(8))) unsigned short u16x8;
typedef __attribute__((ext_vector_type(4))) float     f32x4;
typedef unsigned long long u64;

__device__ inline unsigned short f2bf(float f) {
    unsigned int u = __float_as_uint(f);
    unsigned int r = u + 0x7FFFu + ((u >> 16) & 1u);
    return (unsigned short)(r >> 16);
}
__device__ inline float bf2f(unsigned short w) {
    return __uint_as_float(((unsigned int)w) << 16);
}

// ---------------------------------------------------------------------------
// WhhT_bf16[j][h] = bf16(W_h[h][700 + j]);  row 1024 is a zero sentinel row.
// ---------------------------------------------------------------------------
__global__ __launch_bounds__(256)
void trans_whh_bf16(const float* __restrict__ W_h, unsigned short* __restrict__ WhhT) {
    __shared__ float tile[32][33];
    const int bx = blockIdx.x * 32;  // h base
    const int by = blockIdx.y * 32;  // j base
    const int tx = threadIdx.x, ty = threadIdx.y;
#pragma unroll
    for (int i = 0; i < 32; i += 8)
        tile[ty + i][tx] = W_h[(size_t)(bx + ty + i) * W_LD + IN_DIM + by + tx];
    __syncthreads();
#pragma unroll
    for (int i = 0; i < 32; i += 8)
        WhhT[(size_t)(by + ty + i) * HID + bx + tx] = f2bf(tile[tx][ty + i]);
}

// WoT[h][o] = Wo[o][h]
__global__ __launch_bounds__(256)
void trans_wo(const float* __restrict__ Wo, float* __restrict__ WoT) {
    const int h = blockIdx.x * 256 + threadIdx.x;
    if (h >= HID) return;
#pragma unroll
    for (int o = 0; o < OUT_DIM; ++o)
        WoT[(size_t)h * OUT_DIM + o] = Wo[(size_t)o * HID + h];
}

// Pack W_h's first 700 cols (ld 1724) -> [1024][704] bf16 (once)
__global__ __launch_bounds__(256)
void pack_w_bf16(const float* __restrict__ W_h, unsigned short* __restrict__ Wp) {
    const int total = HID * (KP / 4);
    for (int idx = blockIdx.x * blockDim.x + threadIdx.x; idx < total;
         idx += gridDim.x * blockDim.x) {
        const int r = idx / (KP / 4);
        const int c = idx - r * (KP / 4);
        ushort4 o = make_ushort4(0, 0, 0, 0);
        if (c < IN_DIM / 4) {
            float4 v = *(const float4*)(W_h + (size_t)r * W_LD + c * 4);
            o = make_ushort4(f2bf(v.x), f2bf(v.y), f2bf(v.z), f2bf(v.w));
        }
        ((ushort4*)Wp)[(size_t)r * (KP / 4) + c] = o;
    }
}

// ---------------------------------------------------------------------------
// GEMM body (r16 verbatim): CUR[m][n] = bf16( sum_k x[m][k]*Wp[n][k] )
// ---------------------------------------------------------------------------
__device__ __forceinline__ u16x8 ldx8(const float* __restrict__ row, int k) {
    u16x8 r;
    if (k <= IN_DIM - 8) {
        float4 a = *(const float4*)(row + k);
        float4 b = *(const float4*)(row + k + 4);
        r[0] = f2bf(a.x); r[1] = f2bf(a.y); r[2] = f2bf(a.z); r[3] = f2bf(a.w);
        r[4] = f2bf(b.x); r[5] = f2bf(b.y); r[6] = f2bf(b.z); r[7] = f2bf(b.w);
    } else if (k < IN_DIM) {
        float4 a = *(const float4*)(row + k);
        r[0] = f2bf(a.x); r[1] = f2bf(a.y); r[2] = f2bf(a.z); r[3] = f2bf(a.w);
        r[4] = 0; r[5] = 0; r[6] = 0; r[7] = 0;
    } else {
        r = (u16x8){0,0,0,0,0,0,0,0};
    }
    return r;
}

__device__ __forceinline__
void gemm_body(char* smem, const float* __restrict__ X,
               const unsigned short* __restrict__ B, unsigned short* __restrict__ C,
               int bm, int bn) {
    unsigned short* lA = (unsigned short*)smem;
    unsigned short* lB = (unsigned short*)(smem + 8192);
    const int tid  = threadIdx.x;
    const int wid  = tid >> 6, lane = tid & 63;
    const int wr   = wid >> 1, wc = wid & 1;

    const int srow = tid >> 2;
    const int skq  = (tid & 3) * 8;

    const int wb0 = (srow * 64 + (tid & 3) * 16) ^ ((srow & 7) << 4);
    const int wb1 = ((srow + 64) * 64 + (tid & 3) * 16) ^ ((srow & 7) << 4);

    const float* xr0 = X + (size_t)(bm + srow) * IN_DIM;
    const float* xr1 = X + (size_t)(bm + srow + 64) * IN_DIM;
    const unsigned short* pb = B + (size_t)(bn + srow) * KP + skq;

    u16x8 ra0, ra1, rb0, rb1;
    auto ldg = [&](int k0) {
        ra0 = ldx8(xr0, k0 + skq);
        ra1 = ldx8(xr1, k0 + skq);
        rb0 = *(const u16x8*)(pb + k0);
        rb1 = *(const u16x8*)(pb + (size_t)64 * KP + k0);
    };

    const int arow = wr * 64 + (lane & 15);
    const int brow = wc * 64 + (lane & 15);
    const int fq   = (lane >> 4) * 16;

    f32x4 acc[4][4];
#pragma unroll
    for (int m = 0; m < 4; ++m)
#pragma unroll
        for (int n = 0; n < 4; ++n) acc[m][n] = (f32x4){0.f, 0.f, 0.f, 0.f};

    ldg(0);
    for (int kt = 0; kt < NKT; ++kt) {
        *(u16x8*)((char*)lA + wb0) = ra0;
        *(u16x8*)((char*)lA + wb1) = ra1;
        *(u16x8*)((char*)lB + wb0) = rb0;
        *(u16x8*)((char*)lB + wb1) = rb1;
        __syncthreads();
        if (kt + 1 < NKT) ldg((kt + 1) * 32);
        bf16x8 af[4], bf[4];
#pragma unroll
        for (int m = 0; m < 4; ++m) {
            const int row = arow + m * 16;
            af[m] = *(const bf16x8*)((const char*)lA + ((row * 64 + fq) ^ ((row & 7) << 4)));
        }
#pragma unroll
        for (int n = 0; n < 4; ++n) {
            const int row = brow + n * 16;
            bf[n] = *(const bf16x8*)((const char*)lB + ((row * 64 + fq) ^ ((row & 7) << 4)));
        }
#pragma unroll
        for (int m = 0; m < 4; ++m)
#pragma unroll
            for (int n = 0; n < 4; ++n)
                acc[m][n] = __builtin_amdgcn_mfma_f32_16x16x32_bf16(af[m], bf[n], acc[m][n], 0, 0, 0);
        __syncthreads();
    }
#pragma unroll
    for (int m = 0; m < 4; ++m)
#pragma unroll
        for (int r = 0; r < 4; ++r) {
            unsigned short* cp = C + (size_t)(bm + wr * 64 + m * 16 + (lane >> 4) * 4 + r) * HID
                               + bn + wc * 64 + (lane & 15);
#pragma unroll
            for (int n = 0; n < 4; ++n)
                __builtin_nontemporal_store(f2bf(acc[m][n][r]), cp + n * 16);
        }
}

// ---------------------------------------------------------------------------
// Scan body (r16 verbatim): r10 structure, bf16 table + bf16 CUR.
// ---------------------------------------------------------------------------
#define G_LDIDX(JJ, g)                                                        \
    {                                                                         \
        const int base_ = lo + (g) * 4;                                       \
        JJ[0] = (base_ + 0 < hi) ? (int)lst[base_ + 0] : 1024;                \
        JJ[1] = (base_ + 1 < hi) ? (int)lst[base_ + 1] : 1024;                \
        JJ[2] = (base_ + 2 < hi) ? (int)lst[base_ + 2] : 1024;                \
        JJ[3] = (base_ + 3 < hi) ? (int)lst[base_ + 3] : 1024;                \
    }

#define G_ISSUE(WB, JJ)                                                       \
    {                                                                         \
        _Pragma("unroll")                                                     \
        for (int q_ = 0; q_ < 4; ++q_) {                                      \
            const unsigned int* p_ = Wrow32 + ((size_t)JJ[q_] << 9);          \
            WB[q_ * 2 + 0] = *(const uint4*)p_;                               \
            WB[q_ * 2 + 1] = *(const uint4*)(p_ + 4);                         \
        }                                                                     \
    }

#define G_ACCUM(WB)                                                           \
    {                                                                         \
        _Pragma("unroll")                                                     \
        for (int q_ = 0; q_ < 4; ++q_) {                                      \
            const uint4 w0_ = WB[q_ * 2 + 0];                                 \
            const uint4 w1_ = WB[q_ * 2 + 1];                                 \
            pacc[0][0] += __uint_as_float(w0_.x << 16);                       \
            pacc[0][1] += __uint_as_float(w0_.x & 0xFFFF0000u);               \
            pacc[0][2] += __uint_as_float(w0_.y << 16);                       \
            pacc[0][3] += __uint_as_float(w0_.y & 0xFFFF0000u);               \
            pacc[1][0] += __uint_as_float(w0_.z << 16);                       \
            pacc[1][1] += __uint_as_float(w0_.z & 0xFFFF0000u);               \
            pacc[1][2] += __uint_as_float(w0_.w << 16);                       \
            pacc[1][3] += __uint_as_float(w0_.w & 0xFFFF0000u);               \
            pacc[2][0] += __uint_as_float(w1_.x << 16);                       \
            pacc[2][1] += __uint_as_float(w1_.x & 0xFFFF0000u);               \
            pacc[2][2] += __uint_as_float(w1_.y << 16);                       \
            pacc[2][3] += __uint_as_float(w1_.y & 0xFFFF0000u);               \
            pacc[3][0] += __uint_as_float(w1_.z << 16);                       \
            pacc[3][1] += __uint_as_float(w1_.z & 0xFFFF0000u);               \
            pacc[3][2] += __uint_as_float(w1_.w << 16);                       \
            pacc[3][3] += __uint_as_float(w1_.w & 0xFFFF0000u);               \
        }                                                                     \
    }

__device__ __forceinline__
void scan_body(char* smem, const unsigned short* __restrict__ CUR,
               const unsigned short* __restrict__ WhhT,
               const float* __restrict__ tau_mem, const float* __restrict__ tau_adp,
               float* __restrict__ zS, float* __restrict__ uS, float* __restrict__ aS,
               float* __restrict__ spkS, unsigned short* __restrict__ masks16,
               int t0, int tc) {
    const int tid  = threadIdx.x;
    const int wv   = tid >> 6;
    const int lane = tid & 63;
    const int b    = blockIdx.x;
    const int h0   = lane * 16;

    unsigned short (*s_idx)[2][1040] = (unsigned short (*)[2][1040])smem;
    f32x4 (*s_part)[4][64]           = (f32x4 (*)[4][64])(smem + 16640);

    float u[16], a[16], alpha[16], rho[16];
#pragma unroll
    for (int q = 0; q < 4; ++q) {
        f32x4 uu = *(const f32x4*)(uS + (size_t)b * HID + h0 + q * 4);
        f32x4 aa = *(const f32x4*)(aS + (size_t)b * HID + h0 + q * 4);
        f32x4 tm = *(const f32x4*)(tau_mem + h0 + q * 4);
        f32x4 ta = *(const f32x4*)(tau_adp + h0 + q * 4);
#pragma unroll
        for (int k = 0; k < 4; ++k) {
            u[q * 4 + k] = uu[k];  a[q * 4 + k] = aa[k];
            alpha[q * 4 + k] = expf(-1.f / tm[k]);
            rho[q * 4 + k]   = expf(-1.f / ta[k]);
        }
    }
    unsigned int zb = 0;
#pragma unroll
    for (int q = 0; q < 4; ++q) {
        f32x4 zz = *(const f32x4*)(zS + (size_t)b * HID + h0 + q * 4);
#pragma unroll
        for (int k = 0; k < 4; ++k)
            if (zz[k] > 0.5f) zb |= (1u << (q * 4 + k));
    }

    int n;
    {
        const int cnt = __popc(zb);
        int incl = cnt;
#pragma unroll
        for (int d = 1; d < 64; d <<= 1) {
            int v = __shfl_up(incl, d, 64);
            if (lane >= d) incl += v;
        }
        int off = incl - cnt;
        unsigned int tmp = zb;
        while (tmp) {
            const int k = __ffs(tmp) - 1;
            tmp &= tmp - 1;
            s_idx[wv][0][off++] = (unsigned short)(h0 + k);
        }
        n = __shfl(incl, 63, 64);
    }

    const unsigned int* Wrow32 = (const unsigned int*)WhhT + (h0 >> 1);
    float xc[16];
    {
        const unsigned short* p = CUR + (size_t)b * HID + h0;
        u16x8 v0 = *(const u16x8*)p;
        u16x8 v1 = *(const u16x8*)(p + 8);
#pragma unroll
        for (int k = 0; k < 8; ++k) {
            xc[k]     = bf2f((unsigned short)v0[k]);
            xc[k + 8] = bf2f((unsigned short)v1[k]);
        }
    }
    __syncthreads();

    int cur = 0;
    int wspk = 0;
    for (int tt = 0; tt < tc; ++tt) {
        float xn[16];
        {
            const int tn = (tt + 1 < tc) ? tt + 1 : tt;
            const unsigned short* p = CUR + ((size_t)tn * BATCH + b) * HID + h0;
            u16x8 v0 = *(const u16x8*)p;
            u16x8 v1 = *(const u16x8*)(p + 8);
#pragma unroll
            for (int k = 0; k < 8; ++k) {
                xn[k]     = bf2f((unsigned short)v0[k]);
                xn[k + 8] = bf2f((unsigned short)v1[k]);
            }
        }

        f32x4 pacc[4];
#pragma unroll
        for (int q = 0; q < 4; ++q) pacc[q] = (f32x4){0.f, 0.f, 0.f, 0.f};

        if (n > 0) {
            const unsigned short* lst = s_idx[wv][cur];
            const int lo = (n * wv) >> 2;
            const int hi = (n * (wv + 1)) >> 2;
            const int m = hi - lo;
            if (m > 0) {
                const int ng = (m + 3) >> 2;
                int  jA[4], jB[4];
                uint4 wA[8], wB[8];
                G_LDIDX(jA, 0);
                G_ISSUE(wA, jA);
                int g = 0;
                while (true) {
                    if (g + 1 < ng) { G_LDIDX(jB, g + 1); G_ISSUE(wB, jB); }
                    G_ACCUM(wA);
                    if (++g >= ng) break;
                    if (g + 1 < ng) { G_LDIDX(jA, g + 1); G_ISSUE(wA, jA); }
                    G_ACCUM(wB);
                    if (++g >= ng) break;
                }
            }
            s_part[wv][0][lane] = pacc[0];
            s_part[wv][1][lane] = pacc[1];
            s_part[wv][2][lane] = pacc[2];
            s_part[wv][3][lane] = pacc[3];
            __syncthreads();
#pragma unroll
            for (int q = 0; q < 4; ++q) {
                f32x4 r0 = s_part[0][q][lane];
                f32x4 r1 = s_part[1][q][lane];
                f32x4 r2 = s_part[2][q][lane];
                f32x4 r3 = s_part[3][q][lane];
                pacc[q] = ((r0 + r1) + r2) + r3;   // fixed wave order
            }
        }

        unsigned int znb = 0;
#pragma unroll
        for (int k = 0; k < 16; ++k) {
            const float rec = pacc[k >> 2][k & 3];
            const float z   = (zb >> k) & 1 ? 1.f : 0.f;
            const float omr = 1.f - rho[k];
            const float oma = 1.f - alpha[k];
            a[k] = rho[k] * a[k] + omr * z;
            const float th = 0.01f + 1.8f * a[k];
            u[k] = alpha[k] * u[k] + oma * (xc[k] + rec) - z * th;
            if (u[k] - th > 0.f) znb |= (1u << k);
        }
        zb = znb;
        wspk += __popc(zb);
        if (wv == 0)
            masks16[((size_t)(t0 + tt) * BATCH + b) * 64 + lane] = (unsigned short)zb;

        {
            const int cnt = __popc(zb);
            int incl = cnt;
#pragma unroll
            for (int d = 1; d < 64; d <<= 1) {
                int v = __shfl_up(incl, d, 64);
                if (lane >= d) incl += v;
            }
            int off = incl - cnt;
            unsigned int tmp = zb;
            while (tmp) {
                const int k = __ffs(tmp) - 1;
                tmp &= tmp - 1;
                s_idx[wv][cur ^ 1][off++] = (unsigned short)(h0 + k);
            }
            n = __shfl(incl, 63, 64);
        }
#pragma unroll
        for (int k = 0; k < 16; ++k) xc[k] = xn[k];
        __syncthreads();
        cur ^= 1;
    }

    if (wv == 0) {
#pragma unroll
        for (int k = 0; k < 16; ++k) {
            zS[(size_t)b * HID + h0 + k] = (zb >> k) & 1 ? 1.f : 0.f;
            uS[(size_t)b * HID + h0 + k] = u[k];
            aS[(size_t)b * HID + h0 + k] = a[k];
        }
#pragma unroll
        for (int d = 32; d > 0; d >>= 1) wspk += __shfl_down(wspk, d, 64);
        if (lane == 0) atomicAdd(spkS, (float)wspk);
    }
}

// ---------------------------------------------------------------------------
// Readout body: one wave per (t,b) pair; y[pr][o] = sum_spiking_j WoT[j][o]
// ---------------------------------------------------------------------------
__device__ __forceinline__
void readout_body(const u64* __restrict__ masks, const float* __restrict__ WoT,
                  float* __restrict__ y, int pr) {
    const int lane = threadIdx.x & 63;
    const u64* mp = masks + (size_t)pr * 16;
    float acc = 0.f;
#pragma unroll 4
    for (int w = 0; w < 16; ++w) {
        u64 m = mp[w];
        while (m) {
            const int j = __ffsll((unsigned long long)m) - 1;
            m &= m - 1;
            if (lane < OUT_DIM) acc += WoT[(size_t)(w * 64 + j) * OUT_DIM + lane];
        }
    }
    if (lane < OUT_DIM) y[(size_t)pr * OUT_DIM + lane] = acc;
}

// ---------------------------------------------------------------------------
// Fused dispatch: [0,256) scan chunk c; [256,256+gemmG) GEMM chunk c+1;
// [256+gemmG, ...) readout of chunk c-1 (masks written by prior dispatch).
// launch_bounds(256,2): 2 blocks/CU -> co-residency (r15-verified).
// ---------------------------------------------------------------------------
__global__ __launch_bounds__(256, 2)
void fused_scan_gemm(const unsigned short* __restrict__ CUR,
                     const unsigned short* __restrict__ WhhT,
                     const float* __restrict__ tau_mem, const float* __restrict__ tau_adp,
                     float* __restrict__ zS, float* __restrict__ uS, float* __restrict__ aS,
                     float* __restrict__ spkS, unsigned short* __restrict__ masks16,
                     int t0, int tc,
                     const float* __restrict__ Xn, const unsigned short* __restrict__ Wp,
                     unsigned short* __restrict__ CURn, int gemmG,
                     const u64* __restrict__ masksAll, const float* __restrict__ WoT,
                     float* __restrict__ yBuf, int pr0, int prN) {
    __shared__ __align__(16) char smem[33024];
    const int bid = (int)blockIdx.x;
    if (bid < BATCH) {
        scan_body(smem, CUR, WhhT, tau_mem, tau_adp, zS, uS, aS, spkS,
                  masks16, t0, tc);
    } else if (bid < BATCH + gemmG) {
        const int gb = bid - BATCH;
        gemm_body(smem, Xn, Wp, CURn, (gb >> 3) * 128, (gb & 7) * 128);
    } else {
        const int rb = bid - BATCH - gemmG;
        const int pi = rb * 4 + ((int)threadIdx.x >> 6);
        if (pi < prN) readout_body(masksAll, WoT, yBuf, pr0 + pi);
    }
}

// Prologue GEMM (chunk 0), same body, n-major grid
__global__ __launch_bounds__(256)
void gemm_pro(const float* __restrict__ X, const unsigned short* __restrict__ Wp,
              unsigned short* __restrict__ C) {
    __shared__ __align__(16) char smem[16384];
    const int gb = (int)blockIdx.x;
    gemm_body(smem, X, Wp, C, (gb >> 3) * 128, (gb & 7) * 128);
}

// Standalone readout (last chunk)
__global__ __launch_bounds__(256)
void readout_y(const u64* __restrict__ masks, const float* __restrict__ WoT,
               float* __restrict__ y, int pr0, int npairs) {
    const int pi = (int)blockIdx.x * 4 + ((int)threadIdx.x >> 6);
    if (pi < npairs) readout_body(masks, WoT, y, pr0 + pi);
}

// ---------------------------------------------------------------------------
// outputs[t][b][o] = EWA over t of y; writes final ouT.
// ---------------------------------------------------------------------------
__global__ __launch_bounds__(256)
void ewa_out(const float* __restrict__ y, const float* __restrict__ tau_out,
             float* __restrict__ outputs, float* __restrict__ ouS) {
    const int idx = blockIdx.x * 256 + threadIdx.x;
    if (idx >= BATCH * OUT_DIM) return;
    const int o = idx % OUT_DIM;
    const float ao = expf(-1.f / tau_out[o]);
    float ou = ouS[idx];
    for (int t = 0; t < T_STEPS; ++t) {
        const float v = y[(size_t)t * BATCH * OUT_DIM + idx];
        ou = ao * ou + (1.f - ao) * v;
        outputs[(size_t)t * BATCH * OUT_DIM + idx] = ou;
    }
    ouS[idx] = ou;
}

// ---------------------------------------------------------------------------
extern "C" void kernel_launch(void* const* d_in, const int* in_sizes, int n_in,
                              void* d_out, int out_size, void* d_ws, size_t ws_size,
                              hipStream_t stream) {
    (void)in_sizes; (void)n_in; (void)out_size; (void)ws_size;
    const float* x       = (const float*)d_in[0];
    const float* W_h     = (const float*)d_in[1];
    const float* tau_mem = (const float*)d_in[2];
    const float* tau_adp = (const float*)d_in[3];
    const float* W_o     = (const float*)d_in[4];
    const float* tau_out = (const float*)d_in[5];

    float* out     = (float*)d_out;
    float* outputs = out;                                      // [250][256][20]
    float* zS  = out + (size_t)T_STEPS * BATCH * OUT_DIM;      // [256][1024]
    float* uS  = zS + (size_t)BATCH * HID;
    float* aS  = uS + (size_t)BATCH * HID;
    float* ouS = aS + (size_t)BATCH * HID;                     // [256][20]
    float* spk = ouS + (size_t)BATCH * OUT_DIM;                // scalar

    // ws layout (bytes): ~74 MB total
    char* w = (char*)d_ws;
    unsigned short* WhhT = (unsigned short*)w; w += (size_t)(HID + 1) * HID * 2;  // 2 MB + zero row
    unsigned short* Wp   = (unsigned short*)w; w += (size_t)HID * KP * 2;         // 1.4 MB
    float*          WoT  = (float*)w;          w += (size_t)HID * OUT_DIM * 4;    // 80 KB
    unsigned short* masks16 = (unsigned short*)w; w += (size_t)T_STEPS * BATCH * 128; // 8 MB
    float*          yBuf = (float*)w;          w += (size_t)T_STEPS * BATCH * OUT_DIM * 4; // 5 MB
    unsigned short* CUR_A = (unsigned short*)w; w += (size_t)MAXCT * BATCH * HID * 2;   // 28.9 MB
    unsigned short* CUR_B = (unsigned short*)w;                                          // 28.9 MB

    // chunk schedule: small chunk 0 minimizes the un-hideable prologue GEMM
    const int tcArr[5] = {30, 55, 55, 55, 55};
    int t0Arr[5];
    t0Arr[0] = 0;
    for (int c = 1; c < 5; ++c) t0Arr[c] = t0Arr[c - 1] + tcArr[c - 1];

    hipMemsetAsync(zS, 0,
                   ((size_t)3 * BATCH * HID + BATCH * OUT_DIM + 1) * sizeof(float),
                   stream);
    hipMemsetAsync(WhhT + (size_t)HID * HID, 0, HID * sizeof(unsigned short), stream);
    trans_whh_bf16<<<dim3(32, 32), dim3(32, 8), 0, stream>>>(W_h, WhhT);
    pack_w_bf16<<<512, 256, 0, stream>>>(W_h, Wp);
    trans_wo<<<4, 256, 0, stream>>>(W_o, WoT);

    // chunk 0 GEMM (30 steps; reads x directly, converts to bf16 in-register)
    gemm_pro<<<2 * tcArr[0] * 8, 256, 0, stream>>>(x, Wp, CUR_A);

    for (int c = 0; c < 5; ++c) {
        const int t0 = t0Arr[c];
        const int tc = tcArr[c];
        unsigned short* CURc = (c & 1) ? CUR_B : CUR_A;
        unsigned short* CURn = (c & 1) ? CUR_A : CUR_B;
        const int gemmG = (c + 1 < 5) ? 2 * tcArr[c + 1] * 8 : 0;
        const int pr0   = (c > 0) ? t0Arr[c - 1] * BATCH : 0;
        const int prN   = (c > 0) ? tcArr[c - 1] * BATCH : 0;
        const int roG   = (prN + 3) / 4;
        const float* Xn = (c + 1 < 5)
                        ? x + (size_t)t0Arr[c + 1] * BATCH * IN_DIM : x;
        fused_scan_gemm<<<BATCH + gemmG + roG, 256, 0, stream>>>(
            CURc, WhhT, tau_mem, tau_adp, zS, uS, aS, spk, masks16,
            t0, tc, Xn, Wp, CURn, gemmG,
            (const u64*)masks16, WoT, yBuf, pr0, prN);
    }

    // readout of the final chunk, then the EWA pass
    const int pr0L = t0Arr[4] * BATCH;
    const int prNL = tcArr[4] * BATCH;
    readout_y<<<(prNL + 3) / 4, 256, 0, stream>>>((const u64*)masks16, WoT,
                                                  yBuf, pr0L, prNL);
    ewa_out<<<(BATCH * OUT_DIM + 255) / 256, 256, 0, stream>>>(yBuf, tau_out, outputs, ouS);
}

// Round 18
// 978.531 us; speedup vs baseline: 1.0233x; 1.0233x over previous
//
#include <hip/hip_runtime.h>

#define T_STEPS 250
#define BATCH   256
#define IN_DIM  700
#define HID     1024
#define W_LD    1724   // = IN_DIM + HID
#define OUT_DIM 20
#define KP      704    // K padded to 22*32
#define NKT     (KP / 32)
#define CHUNK_T 50     // 5 chunks of 50 steps

typedef __attribute__((ext_vector_type(8))) short     bf16x8;
typedef __attribute__((ext_vector_type(8))) unsigned short u16x8;
typedef __attribute__((ext_vector_type(4))) float     f32x4;
typedef unsigned long long u64;

__device__ inline unsigned short f2bf(float f) {
    unsigned int u = __float_as_uint(f);
    unsigned int r = u + 0x7FFFu + ((u >> 16) & 1u);
    return (unsigned short)(r >> 16);
}
__device__ inline float bf2f(unsigned short w) {
    return __uint_as_float(((unsigned int)w) << 16);
}

// ---------------------------------------------------------------------------
// WhhT_bf16[j][h] = bf16(W_h[h][700 + j]);  row 1024 is a zero sentinel row.
// ---------------------------------------------------------------------------
__global__ __launch_bounds__(256)
void trans_whh_bf16(const float* __restrict__ W_h, unsigned short* __restrict__ WhhT) {
    __shared__ float tile[32][33];
    const int bx = blockIdx.x * 32;  // h base
    const int by = blockIdx.y * 32;  // j base
    const int tx = threadIdx.x, ty = threadIdx.y;
#pragma unroll
    for (int i = 0; i < 32; i += 8)
        tile[ty + i][tx] = W_h[(size_t)(bx + ty + i) * W_LD + IN_DIM + by + tx];
    __syncthreads();
#pragma unroll
    for (int i = 0; i < 32; i += 8)
        WhhT[(size_t)(by + ty + i) * HID + bx + tx] = f2bf(tile[tx][ty + i]);
}

// WoT[h][o] = Wo[o][h]
__global__ __launch_bounds__(256)
void trans_wo(const float* __restrict__ Wo, float* __restrict__ WoT) {
    const int h = blockIdx.x * 256 + threadIdx.x;
    if (h >= HID) return;
#pragma unroll
    for (int o = 0; o < OUT_DIM; ++o)
        WoT[(size_t)h * OUT_DIM + o] = Wo[(size_t)o * HID + h];
}

// Pack W_h's first 700 cols (ld 1724) -> [1024][704] bf16 (once)
__global__ __launch_bounds__(256)
void pack_w_bf16(const float* __restrict__ W_h, unsigned short* __restrict__ Wp) {
    const int total = HID * (KP / 4);
    for (int idx = blockIdx.x * blockDim.x + threadIdx.x; idx < total;
         idx += gridDim.x * blockDim.x) {
        const int r = idx / (KP / 4);
        const int c = idx - r * (KP / 4);
        ushort4 o = make_ushort4(0, 0, 0, 0);
        if (c < IN_DIM / 4) {
            float4 v = *(const float4*)(W_h + (size_t)r * W_LD + c * 4);
            o = make_ushort4(f2bf(v.x), f2bf(v.y), f2bf(v.z), f2bf(v.w));
        }
        ((ushort4*)Wp)[(size_t)r * (KP / 4) + c] = o;
    }
}

// ---------------------------------------------------------------------------
// GEMM body: CUR[m][n] = bf16( sum_k x[m][k]*Wp[n][k] ); A-side reads x as
// FLOAT, converts bf16 in registers. Output stored as BF16 NONTEMPORAL
// (write-once stream; halves CUR traffic and keeps it out of L2 so the
// scan's weight table stays resident). 128x128 tile, BK=32, 4 waves.
// ---------------------------------------------------------------------------
__device__ __forceinline__ u16x8 ldx8(const float* __restrict__ row, int k) {
    u16x8 r;
    if (k <= IN_DIM - 8) {
        float4 a = *(const float4*)(row + k);
        float4 b = *(const float4*)(row + k + 4);
        r[0] = f2bf(a.x); r[1] = f2bf(a.y); r[2] = f2bf(a.z); r[3] = f2bf(a.w);
        r[4] = f2bf(b.x); r[5] = f2bf(b.y); r[6] = f2bf(b.z); r[7] = f2bf(b.w);
    } else if (k < IN_DIM) {  // k == 696: 4 valid + 4 zero
        float4 a = *(const float4*)(row + k);
        r[0] = f2bf(a.x); r[1] = f2bf(a.y); r[2] = f2bf(a.z); r[3] = f2bf(a.w);
        r[4] = 0; r[5] = 0; r[6] = 0; r[7] = 0;
    } else {
        r = (u16x8){0,0,0,0,0,0,0,0};
    }
    return r;
}

__device__ __forceinline__
void gemm_body(char* smem, const float* __restrict__ X,
               const unsigned short* __restrict__ B, unsigned short* __restrict__ C,
               int bm, int bn) {
    unsigned short* lA = (unsigned short*)smem;            // 8192 B
    unsigned short* lB = (unsigned short*)(smem + 8192);   // 8192 B
    const int tid  = threadIdx.x;
    const int wid  = tid >> 6, lane = tid & 63;
    const int wr   = wid >> 1, wc = wid & 1;

    const int srow = tid >> 2;
    const int skq  = (tid & 3) * 8;

    const int wb0 = (srow * 64 + (tid & 3) * 16) ^ ((srow & 7) << 4);
    const int wb1 = ((srow + 64) * 64 + (tid & 3) * 16) ^ ((srow & 7) << 4);

    const float* xr0 = X + (size_t)(bm + srow) * IN_DIM;
    const float* xr1 = X + (size_t)(bm + srow + 64) * IN_DIM;
    const unsigned short* pb = B + (size_t)(bn + srow) * KP + skq;

    u16x8 ra0, ra1, rb0, rb1;
    auto ldg = [&](int k0) {
        ra0 = ldx8(xr0, k0 + skq);
        ra1 = ldx8(xr1, k0 + skq);
        rb0 = *(const u16x8*)(pb + k0);
        rb1 = *(const u16x8*)(pb + (size_t)64 * KP + k0);
    };

    const int arow = wr * 64 + (lane & 15);
    const int brow = wc * 64 + (lane & 15);
    const int fq   = (lane >> 4) * 16;

    f32x4 acc[4][4];
#pragma unroll
    for (int m = 0; m < 4; ++m)
#pragma unroll
        for (int n = 0; n < 4; ++n) acc[m][n] = (f32x4){0.f, 0.f, 0.f, 0.f};

    ldg(0);
    for (int kt = 0; kt < NKT; ++kt) {
        *(u16x8*)((char*)lA + wb0) = ra0;
        *(u16x8*)((char*)lA + wb1) = ra1;
        *(u16x8*)((char*)lB + wb0) = rb0;
        *(u16x8*)((char*)lB + wb1) = rb1;
        __syncthreads();
        if (kt + 1 < NKT) ldg((kt + 1) * 32);
        bf16x8 af[4], bf[4];
#pragma unroll
        for (int m = 0; m < 4; ++m) {
            const int row = arow + m * 16;
            af[m] = *(const bf16x8*)((const char*)lA + ((row * 64 + fq) ^ ((row & 7) << 4)));
        }
#pragma unroll
        for (int n = 0; n < 4; ++n) {
            const int row = brow + n * 16;
            bf[n] = *(const bf16x8*)((const char*)lB + ((row * 64 + fq) ^ ((row & 7) << 4)));
        }
#pragma unroll
        for (int m = 0; m < 4; ++m)
#pragma unroll
            for (int n = 0; n < 4; ++n)
                acc[m][n] = __builtin_amdgcn_mfma_f32_16x16x32_bf16(af[m], bf[n], acc[m][n], 0, 0, 0);
        __syncthreads();
    }
#pragma unroll
    for (int m = 0; m < 4; ++m)
#pragma unroll
        for (int r = 0; r < 4; ++r) {
            unsigned short* cp = C + (size_t)(bm + wr * 64 + m * 16 + (lane >> 4) * 4 + r) * HID
                               + bn + wc * 64 + (lane & 15);
#pragma unroll
            for (int n = 0; n < 4; ++n)
                __builtin_nontemporal_store(f2bf(acc[m][n][r]), cp + n * 16);
        }
}

// ---------------------------------------------------------------------------
// Scan body: r10 structure — 1 block = 1 batch, 4 waves split by SOURCE
// spike-list quarter, 16 neurons/lane, bf16 table, LDS partial exchange
// (fixed wave order), update replicated. CUR bf16 (bit-exact shift decode).
// ---------------------------------------------------------------------------
#define G_LDIDX(JJ, g)                                                        \
    {                                                                         \
        const int base_ = lo + (g) * 4;                                       \
        JJ[0] = (base_ + 0 < hi) ? (int)lst[base_ + 0] : 1024;                \
        JJ[1] = (base_ + 1 < hi) ? (int)lst[base_ + 1] : 1024;                \
        JJ[2] = (base_ + 2 < hi) ? (int)lst[base_ + 2] : 1024;                \
        JJ[3] = (base_ + 3 < hi) ? (int)lst[base_ + 3] : 1024;                \
    }

#define G_ISSUE(WB, JJ)                                                       \
    {                                                                         \
        _Pragma("unroll")                                                     \
        for (int q_ = 0; q_ < 4; ++q_) {                                      \
            const unsigned int* p_ = Wrow32 + ((size_t)JJ[q_] << 9);          \
            WB[q_ * 2 + 0] = *(const uint4*)p_;                               \
            WB[q_ * 2 + 1] = *(const uint4*)(p_ + 4);                         \
        }                                                                     \
    }

#define G_ACCUM(WB)                                                           \
    {                                                                         \
        _Pragma("unroll")                                                     \
        for (int q_ = 0; q_ < 4; ++q_) {                                      \
            const uint4 w0_ = WB[q_ * 2 + 0];                                 \
            const uint4 w1_ = WB[q_ * 2 + 1];                                 \
            pacc[0][0] += __uint_as_float(w0_.x << 16);                       \
            pacc[0][1] += __uint_as_float(w0_.x & 0xFFFF0000u);               \
            pacc[0][2] += __uint_as_float(w0_.y << 16);                       \
            pacc[0][3] += __uint_as_float(w0_.y & 0xFFFF0000u);               \
            pacc[1][0] += __uint_as_float(w0_.z << 16);                       \
            pacc[1][1] += __uint_as_float(w0_.z & 0xFFFF0000u);               \
            pacc[1][2] += __uint_as_float(w0_.w << 16);                       \
            pacc[1][3] += __uint_as_float(w0_.w & 0xFFFF0000u);               \
            pacc[2][0] += __uint_as_float(w1_.x << 16);                       \
            pacc[2][1] += __uint_as_float(w1_.x & 0xFFFF0000u);               \
            pacc[2][2] += __uint_as_float(w1_.y << 16);                       \
            pacc[2][3] += __uint_as_float(w1_.y & 0xFFFF0000u);               \
            pacc[3][0] += __uint_as_float(w1_.z << 16);                       \
            pacc[3][1] += __uint_as_float(w1_.z & 0xFFFF0000u);               \
            pacc[3][2] += __uint_as_float(w1_.w << 16);                       \
            pacc[3][3] += __uint_as_float(w1_.w & 0xFFFF0000u);               \
        }                                                                     \
    }

__device__ __forceinline__
void scan_body(char* smem, const unsigned short* __restrict__ CUR,
               const unsigned short* __restrict__ WhhT,
               const float* __restrict__ tau_mem, const float* __restrict__ tau_adp,
               float* __restrict__ zS, float* __restrict__ uS, float* __restrict__ aS,
               float* __restrict__ spkS, unsigned short* __restrict__ masks16,
               int t0, int tc) {
    const int tid  = threadIdx.x;
    const int wv   = tid >> 6;
    const int lane = tid & 63;
    const int b    = blockIdx.x;
    const int h0   = lane * 16;

    unsigned short (*s_idx)[2][1040] = (unsigned short (*)[2][1040])smem;      // 16640 B
    f32x4 (*s_part)[4][64]           = (f32x4 (*)[4][64])(smem + 16640);       // 16384 B

    float u[16], a[16], alpha[16], rho[16];
#pragma unroll
    for (int q = 0; q < 4; ++q) {
        f32x4 uu = *(const f32x4*)(uS + (size_t)b * HID + h0 + q * 4);
        f32x4 aa = *(const f32x4*)(aS + (size_t)b * HID + h0 + q * 4);
        f32x4 tm = *(const f32x4*)(tau_mem + h0 + q * 4);
        f32x4 ta = *(const f32x4*)(tau_adp + h0 + q * 4);
#pragma unroll
        for (int k = 0; k < 4; ++k) {
            u[q * 4 + k] = uu[k];  a[q * 4 + k] = aa[k];
            alpha[q * 4 + k] = expf(-1.f / tm[k]);
            rho[q * 4 + k]   = expf(-1.f / ta[k]);
        }
    }
    unsigned int zb = 0;
#pragma unroll
    for (int q = 0; q < 4; ++q) {
        f32x4 zz = *(const f32x4*)(zS + (size_t)b * HID + h0 + q * 4);
#pragma unroll
        for (int k = 0; k < 4; ++k)
            if (zz[k] > 0.5f) zb |= (1u << (q * 4 + k));
    }

    int n;
    {
        const int cnt = __popc(zb);
        int incl = cnt;
#pragma unroll
        for (int d = 1; d < 64; d <<= 1) {
            int v = __shfl_up(incl, d, 64);
            if (lane >= d) incl += v;
        }
        int off = incl - cnt;
        unsigned int tmp = zb;
        while (tmp) {
            const int k = __ffs(tmp) - 1;
            tmp &= tmp - 1;
            s_idx[wv][0][off++] = (unsigned short)(h0 + k);
        }
        n = __shfl(incl, 63, 64);
    }

    const unsigned int* Wrow32 = (const unsigned int*)WhhT + (h0 >> 1);
    float xc[16];
    {
        const unsigned short* p = CUR + (size_t)b * HID + h0;
        u16x8 v0 = *(const u16x8*)p;
        u16x8 v1 = *(const u16x8*)(p + 8);
#pragma unroll
        for (int k = 0; k < 8; ++k) {
            xc[k]     = bf2f((unsigned short)v0[k]);
            xc[k + 8] = bf2f((unsigned short)v1[k]);
        }
    }
    __syncthreads();

    int cur = 0;
    int wspk = 0;
    for (int tt = 0; tt < tc; ++tt) {
        float xn[16];
        {
            const int tn = (tt + 1 < tc) ? tt + 1 : tt;
            const unsigned short* p = CUR + ((size_t)tn * BATCH + b) * HID + h0;
            u16x8 v0 = *(const u16x8*)p;
            u16x8 v1 = *(const u16x8*)(p + 8);
#pragma unroll
            for (int k = 0; k < 8; ++k) {
                xn[k]     = bf2f((unsigned short)v0[k]);
                xn[k + 8] = bf2f((unsigned short)v1[k]);
            }
        }

        f32x4 pacc[4];
#pragma unroll
        for (int q = 0; q < 4; ++q) pacc[q] = (f32x4){0.f, 0.f, 0.f, 0.f};

        if (n > 0) {
            const unsigned short* lst = s_idx[wv][cur];
            const int lo = (n * wv) >> 2;
            const int hi = (n * (wv + 1)) >> 2;
            const int m = hi - lo;
            if (m > 0) {
                const int ng = (m + 3) >> 2;
                int  jA[4], jB[4];
                uint4 wA[8], wB[8];
                G_LDIDX(jA, 0);
                G_ISSUE(wA, jA);
                int g = 0;
                while (true) {
                    if (g + 1 < ng) { G_LDIDX(jB, g + 1); G_ISSUE(wB, jB); }
                    G_ACCUM(wA);
                    if (++g >= ng) break;
                    if (g + 1 < ng) { G_LDIDX(jA, g + 1); G_ISSUE(wA, jA); }
                    G_ACCUM(wB);
                    if (++g >= ng) break;
                }
            }
            s_part[wv][0][lane] = pacc[0];
            s_part[wv][1][lane] = pacc[1];
            s_part[wv][2][lane] = pacc[2];
            s_part[wv][3][lane] = pacc[3];
            __syncthreads();
#pragma unroll
            for (int q = 0; q < 4; ++q) {
                f32x4 r0 = s_part[0][q][lane];
                f32x4 r1 = s_part[1][q][lane];
                f32x4 r2 = s_part[2][q][lane];
                f32x4 r3 = s_part[3][q][lane];
                pacc[q] = ((r0 + r1) + r2) + r3;   // fixed wave order
            }
        }

        unsigned int znb = 0;
#pragma unroll
        for (int k = 0; k < 16; ++k) {
            const float rec = pacc[k >> 2][k & 3];
            const float z   = (zb >> k) & 1 ? 1.f : 0.f;
            const float omr = 1.f - rho[k];
            const float oma = 1.f - alpha[k];
            a[k] = rho[k] * a[k] + omr * z;
            const float th = 0.01f + 1.8f * a[k];
            u[k] = alpha[k] * u[k] + oma * (xc[k] + rec) - z * th;
            if (u[k] - th > 0.f) znb |= (1u << k);
        }
        zb = znb;
        wspk += __popc(zb);
        if (wv == 0)
            masks16[((size_t)(t0 + tt) * BATCH + b) * 64 + lane] = (unsigned short)zb;

        {
            const int cnt = __popc(zb);
            int incl = cnt;
#pragma unroll
            for (int d = 1; d < 64; d <<= 1) {
                int v = __shfl_up(incl, d, 64);
                if (lane >= d) incl += v;
            }
            int off = incl - cnt;
            unsigned int tmp = zb;
            while (tmp) {
                const int k = __ffs(tmp) - 1;
                tmp &= tmp - 1;
                s_idx[wv][cur ^ 1][off++] = (unsigned short)(h0 + k);
            }
            n = __shfl(incl, 63, 64);
        }
#pragma unroll
        for (int k = 0; k < 16; ++k) xc[k] = xn[k];
        __syncthreads();
        cur ^= 1;
    }

    if (wv == 0) {
#pragma unroll
        for (int k = 0; k < 16; ++k) {
            zS[(size_t)b * HID + h0 + k] = (zb >> k) & 1 ? 1.f : 0.f;
            uS[(size_t)b * HID + h0 + k] = u[k];
            aS[(size_t)b * HID + h0 + k] = a[k];
        }
#pragma unroll
        for (int d = 32; d > 0; d >>= 1) wspk += __shfl_down(wspk, d, 64);
        if (lane == 0) atomicAdd(spkS, (float)wspk);
    }
}

// ---------------------------------------------------------------------------
// Fused dispatch: blocks 0..255 = scan chunk i; blocks 256.. = GEMM chunk i+1
// launch_bounds(256,2) allows 2 blocks/CU -> true co-residency (r15 verified:
// occupancy 10.8 -> 18.7%). GEMM grid is n-major (gb&7 = bn) so the 8 blocks
// sharing an x-panel run adjacently -> x read once from HBM, L2 stays clean
// for the scan's 2MB weight table.
// ---------------------------------------------------------------------------
__global__ __launch_bounds__(256, 2)
void fused_scan_gemm(const unsigned short* __restrict__ CUR,
                     const unsigned short* __restrict__ WhhT,
                     const float* __restrict__ tau_mem, const float* __restrict__ tau_adp,
                     float* __restrict__ zS, float* __restrict__ uS, float* __restrict__ aS,
                     float* __restrict__ spkS, unsigned short* __restrict__ masks16,
                     int t0, int tc,
                     const float* __restrict__ Xn, const unsigned short* __restrict__ Wp,
                     unsigned short* __restrict__ CURn) {
    __shared__ __align__(16) char smem[33024];
    if ((int)blockIdx.x < BATCH) {
        scan_body(smem, CUR, WhhT, tau_mem, tau_adp, zS, uS, aS, spkS,
                  masks16, t0, tc);
    } else {
        const int gb = (int)blockIdx.x - BATCH;
        gemm_body(smem, Xn, Wp, CURn, (gb >> 3) * 128, (gb & 7) * 128);
    }
}

// Prologue GEMM (chunk 0), same body, n-major grid
__global__ __launch_bounds__(256)
void gemm_pro(const float* __restrict__ X, const unsigned short* __restrict__ Wp,
              unsigned short* __restrict__ C) {
    __shared__ __align__(16) char smem[16384];
    const int gb = (int)blockIdx.x;
    gemm_body(smem, X, Wp, C, (gb >> 3) * 128, (gb & 7) * 128);
}

// ---------------------------------------------------------------------------
// y[t*B+b][o] = sum over spiking j of WoT[j][o]  (one wave per (t,b) pair)
// ---------------------------------------------------------------------------
__global__ __launch_bounds__(256)
void readout_y(const u64* __restrict__ masks, const float* __restrict__ WoT,
               float* __restrict__ y, int npairs) {
    const int pr   = blockIdx.x * 4 + (threadIdx.x >> 6);
    const int lane = threadIdx.x & 63;
    if (pr >= npairs) return;
    const u64* mp = masks + (size_t)pr * 16;
    float acc = 0.f;
#pragma unroll 4
    for (int w = 0; w < 16; ++w) {
        u64 m = mp[w];
        while (m) {
            const int j = __ffsll((unsigned long long)m) - 1;
            m &= m - 1;
            if (lane < OUT_DIM) acc += WoT[(size_t)(w * 64 + j) * OUT_DIM + lane];
        }
    }
    if (lane < OUT_DIM) y[(size_t)pr * OUT_DIM + lane] = acc;
}

// ---------------------------------------------------------------------------
// outputs[t][b][o] = EWA over t of y; writes final ouT.
// ---------------------------------------------------------------------------
__global__ __launch_bounds__(256)
void ewa_out(const float* __restrict__ y, const float* __restrict__ tau_out,
             float* __restrict__ outputs, float* __restrict__ ouS) {
    const int idx = blockIdx.x * 256 + threadIdx.x;
    if (idx >= BATCH * OUT_DIM) return;
    const int o = idx % OUT_DIM;
    const float ao = expf(-1.f / tau_out[o]);
    float ou = ouS[idx];
    for (int t = 0; t < T_STEPS; ++t) {
        const float v = y[(size_t)t * BATCH * OUT_DIM + idx];
        ou = ao * ou + (1.f - ao) * v;
        outputs[(size_t)t * BATCH * OUT_DIM + idx] = ou;
    }
    ouS[idx] = ou;
}

// ---------------------------------------------------------------------------
extern "C" void kernel_launch(void* const* d_in, const int* in_sizes, int n_in,
                              void* d_out, int out_size, void* d_ws, size_t ws_size,
                              hipStream_t stream) {
    (void)in_sizes; (void)n_in; (void)out_size; (void)ws_size;
    const float* x       = (const float*)d_in[0];
    const float* W_h     = (const float*)d_in[1];
    const float* tau_mem = (const float*)d_in[2];
    const float* tau_adp = (const float*)d_in[3];
    const float* W_o     = (const float*)d_in[4];
    const float* tau_out = (const float*)d_in[5];

    float* out     = (float*)d_out;
    float* outputs = out;                                      // [250][256][20]
    float* zS  = out + (size_t)T_STEPS * BATCH * OUT_DIM;      // [256][1024]
    float* uS  = zS + (size_t)BATCH * HID;
    float* aS  = uS + (size_t)BATCH * HID;
    float* ouS = aS + (size_t)BATCH * HID;                     // [256][20]
    float* spk = ouS + (size_t)BATCH * OUT_DIM;                // scalar

    // ws layout (bytes): ~69 MB total
    char* w = (char*)d_ws;
    unsigned short* WhhT = (unsigned short*)w; w += (size_t)(HID + 1) * HID * 2;  // 2 MB + zero row
    unsigned short* Wp   = (unsigned short*)w; w += (size_t)HID * KP * 2;         // 1.4 MB
    float*          WoT  = (float*)w;          w += (size_t)HID * OUT_DIM * 4;    // 80 KB
    unsigned short* masks16 = (unsigned short*)w; w += (size_t)T_STEPS * BATCH * 128; // 8 MB
    float*          yBuf = (float*)w;          w += (size_t)T_STEPS * BATCH * OUT_DIM * 4; // 5 MB
    unsigned short* CUR_A = (unsigned short*)w; w += (size_t)CHUNK_T * BATCH * HID * 2;   // 26.2 MB
    unsigned short* CUR_B = (unsigned short*)w;                                            // 26.2 MB

    const int mB    = CHUNK_T * BATCH / 128;   // 100
    const int gemmG = mB * (HID / 128);        // 800

    hipMemsetAsync(zS, 0,
                   ((size_t)3 * BATCH * HID + BATCH * OUT_DIM + 1) * sizeof(float),
                   stream);
    hipMemsetAsync(WhhT + (size_t)HID * HID, 0, HID * sizeof(unsigned short), stream);
    trans_whh_bf16<<<dim3(32, 32), dim3(32, 8), 0, stream>>>(W_h, WhhT);
    pack_w_bf16<<<512, 256, 0, stream>>>(W_h, Wp);
    trans_wo<<<4, 256, 0, stream>>>(W_o, WoT);

    // chunk 0 GEMM (reads x directly, converts to bf16 in-register)
    gemm_pro<<<gemmG, 256, 0, stream>>>(x, Wp, CUR_A);

    const int nChunks = T_STEPS / CHUNK_T;     // 5
    for (int c = 0; c < nChunks; ++c) {
        const int t0 = c * CHUNK_T;
        unsigned short* CURc = (c & 1) ? CUR_B : CUR_A;
        unsigned short* CURn = (c & 1) ? CUR_A : CUR_B;
        const bool more = (c + 1 < nChunks);
        const int grid = BATCH + (more ? gemmG : 0);
        fused_scan_gemm<<<grid, 256, 0, stream>>>(
            CURc, WhhT, tau_mem, tau_adp, zS, uS, aS, spk, masks16,
            t0, CHUNK_T,
            x + (size_t)(t0 + CHUNK_T) * BATCH * IN_DIM, Wp, CURn);
    }

    const int npairs = T_STEPS * BATCH;
    readout_y<<<(npairs + 3) / 4, 256, 0, stream>>>((const u64*)masks16, WoT, yBuf, npairs);
    ewa_out<<<(BATCH * OUT_DIM + 255) / 256, 256, 0, stream>>>(yBuf, tau_out, outputs, ouS);
}